// Round 5
// baseline (507.530 us; speedup 1.0000x reference)
//
#include <hip/hip_runtime.h>

// Problem constants
constexpr int CIN  = 32;
constexpr int COUT = 128;
constexpr int ATOM = 64;
constexpr int BB   = 128;
constexpr int COLS_PER_B = COUT * ATOM;              // 8192
constexpr long long NTOT = (long long)BB * COLS_PER_B; // 1,048,576 columns
constexpr float NTOTF = 1048576.0f;

typedef float f32x2 __attribute__((ext_vector_type(2)));

// Stats kernel tiling
constexpr int TK    = 256;     // columns per LDS tile
constexpr int PAD   = 260;     // row stride in floats (x4B=1040B: rows land on banks 4*r%32 -> conflict-free b128)
constexpr int GRID1 = 512;     // 2 persistent blocks/CU
constexpr int TILES = 4096;    // NTOT / TK
constexpr int TPB   = TILES / GRID1; // 8 tiles per block

// ws layout (floats): [0..1023] G accum, [1024..1055] s accum,
//                     [1056..2079] W (invsqrt*gamma), [2080..2111] bias

__global__ __launch_bounds__(256) void stats_kernel(const float* __restrict__ x,
                                                    float* __restrict__ acc) {
    __shared__ float tile[CIN * PAD];   // 33,280 B
    __shared__ float ssum[CIN];
    const int t = threadIdx.x;
    const int w = t >> 6;        // wave id = k-quarter
    const int l = t & 63;
    const int ti = l >> 3;       // 0..7
    const int tj = l & 7;        // 0..7

    float accg[4][4] = {};
    float asum[4] = {0.f, 0.f, 0.f, 0.f};
    if (t < CIN) ssum[t] = 0.f;

    const int tile0 = blockIdx.x * TPB;
    auto srcp = [&](int tileid, int row) -> const float* {
        const int b = tileid >> 5;               // 32 tiles per batch
        const int col0 = (tileid & 31) << 8;     // *256
        return x + (size_t)b * CIN * COLS_PER_B + (size_t)row * COLS_PER_B + col0 + l * 4;
    };

    // prologue: stage tile 0
    float4 stg[8];
    #pragma unroll
    for (int rr = 0; rr < 8; ++rr) stg[rr] = *(const float4*)srcp(tile0, rr * 4 + w);
    #pragma unroll
    for (int rr = 0; rr < 8; ++rr) *(float4*)(&tile[(rr * 4 + w) * PAD + l * 4]) = stg[rr];
    __syncthreads();

    for (int tt = 0; tt < TPB; ++tt) {
        // prefetch next tile into regs (latency hides under compute below)
        if (tt + 1 < TPB) {
            #pragma unroll
            for (int rr = 0; rr < 8; ++rr) stg[rr] = *(const float4*)srcp(tile0 + tt + 1, rr * 4 + w);
        }
        // compute current tile: wave w handles k in [w*64, w*64+64)
        #pragma unroll
        for (int s = 0; s < 16; ++s) {
            const int k = w * 64 + s * 4;
            float4 av[4], bv[4];
            #pragma unroll
            for (int d = 0; d < 4; ++d) av[d] = *(const float4*)(&tile[(ti + 8 * d) * PAD + k]);
            #pragma unroll
            for (int d = 0; d < 4; ++d) bv[d] = *(const float4*)(&tile[(tj + 8 * d) * PAD + k]);
            #pragma unroll
            for (int di = 0; di < 4; ++di) {
                asum[di] += av[di].x + av[di].y + av[di].z + av[di].w;
                #pragma unroll
                for (int dj = 0; dj < 4; ++dj) {
                    accg[di][dj] += av[di].x * bv[dj].x + av[di].y * bv[dj].y
                                  + av[di].z * bv[dj].z + av[di].w * bv[dj].w;
                }
            }
        }
        __syncthreads();   // all waves done READING tile before overwrite
        if (tt + 1 < TPB) {
            #pragma unroll
            for (int rr = 0; rr < 8; ++rr) *(float4*)(&tile[(rr * 4 + w) * PAD + l * 4]) = stg[rr];
        }
        __syncthreads();   // writes visible before next compute
    }

    // cross-wave reduction of G partials via LDS (reuse tile)
    #pragma unroll
    for (int di = 0; di < 4; ++di)
        #pragma unroll
        for (int dj = 0; dj < 4; ++dj)
            tile[w * 1024 + (ti + 8 * di) * 32 + (tj + 8 * dj)] = accg[di][dj];
    if (tj == 0) {
        #pragma unroll
        for (int di = 0; di < 4; ++di) atomicAdd(&ssum[ti + 8 * di], asum[di]);
    }
    __syncthreads();
    #pragma unroll
    for (int q = 0; q < 4; ++q) {
        const int idx = t + q * 256;
        const float v = tile[idx] + tile[1024 + idx] + tile[2048 + idx] + tile[3072 + idx];
        atomicAdd(&acc[idx], v);
    }
    if (t < CIN) atomicAdd(&acc[1024 + t], ssum[t]);
}

__global__ __launch_bounds__(1024) void newton_kernel(const float* __restrict__ acc,
                                                      const float* __restrict__ gamma,
                                                      const float* __restrict__ beta,
                                                      float* __restrict__ outp) {
    __shared__ float sn[32 * 33], p[32 * 33], t1[32 * 33], t2[32 * 33];
    __shared__ float mean[32], diag[32], trs[1];
    const int t = threadIdx.x;
    const int i = t >> 5, j = t & 31;

    if (t < 32) mean[t] = acc[1024 + t] * (1.0f / NTOTF);
    __syncthreads();
    const float sig = (acc[t] - NTOTF * mean[i] * mean[j]) * (1.0f / (NTOTF - 1.0f));
    if (i == j) diag[i] = sig;
    __syncthreads();
    if (t == 0) {
        float tr = 0.f;
        for (int k = 0; k < 32; ++k) tr += diag[k];
        trs[0] = tr;
    }
    __syncthreads();
    const float tr = trs[0];
    sn[i * 33 + j] = sig / tr;
    p[i * 33 + j]  = (i == j) ? 1.0f : 0.0f;
    __syncthreads();

    for (int it = 0; it < 5; ++it) {
        float a = 0.f;
        #pragma unroll
        for (int k = 0; k < 32; ++k) a += p[i * 33 + k] * p[k * 33 + j];
        t1[i * 33 + j] = a;
        __syncthreads();
        float c = 0.f;
        #pragma unroll
        for (int k = 0; k < 32; ++k) c += t1[i * 33 + k] * p[k * 33 + j];
        t2[i * 33 + j] = c;
        __syncthreads();
        float v = 0.f;
        #pragma unroll
        for (int k = 0; k < 32; ++k) v += t2[i * 33 + k] * sn[k * 33 + j];
        const float pn = 1.5f * p[i * 33 + j] - 0.5f * v;
        __syncthreads();
        p[i * 33 + j] = pn;
        __syncthreads();
    }

    const float r = rsqrtf(tr);
    const float wv = p[i * 33 + j] * r * gamma[j];   // fold gamma into W
    t1[i * 33 + j] = wv;
    outp[t] = wv;                                    // W: 1024 floats
    __syncthreads();
    if (t < 32) {
        float bb = beta[t];
        for (int k = 0; k < 32; ++k) bb -= mean[k] * t1[k * 33 + t];
        outp[1024 + t] = bb;                         // bias: 32 floats
    }
}

// float2 per thread: vals[32]=64 VGPR -> ~100 total -> 4 waves/SIMD.
__global__ __launch_bounds__(256, 4) void apply_kernel(const float* __restrict__ x,
                                                       const float* __restrict__ wm,
                                                       float* __restrict__ out) {
    const size_t tid  = (size_t)blockIdx.x * 256 + threadIdx.x;
    const size_t col2 = tid * 2;          // 2 columns per thread
    const size_t b    = col2 >> 13;       // /8192
    const size_t c    = col2 & 8191;
    const float* xp = x + b * (size_t)(CIN * COLS_PER_B) + c;
    float* op       = out + b * (size_t)(CIN * COLS_PER_B) + c;

    float2 vals[32];
    #pragma unroll
    for (int i = 0; i < 32; ++i) vals[i] = *(const float2*)(xp + (size_t)i * COLS_PER_B);

    #pragma unroll
    for (int jb = 0; jb < 4; ++jb) {
        float2 accv[8];
        #pragma unroll
        for (int jj = 0; jj < 8; ++jj) {
            const float bv = wm[1024 + jb * 8 + jj];
            accv[jj] = make_float2(bv, bv);
        }
        #pragma unroll
        for (int i = 0; i < 32; ++i) {
            #pragma unroll
            for (int jj = 0; jj < 8; ++jj) {
                const float sv = wm[i * 32 + jb * 8 + jj];  // wave-uniform -> SGPR broadcast
                accv[jj].x += vals[i].x * sv;
                accv[jj].y += vals[i].y * sv;
            }
        }
        // Nontemporal: keep x resident in L3 (out is write-once, never re-read).
        #pragma unroll
        for (int jj = 0; jj < 8; ++jj) {
            f32x2 v = { accv[jj].x, accv[jj].y };
            __builtin_nontemporal_store(v, (f32x2*)(op + (size_t)(jb * 8 + jj) * COLS_PER_B));
        }
    }
}

extern "C" void kernel_launch(void* const* d_in, const int* in_sizes, int n_in,
                              void* d_out, int out_size, void* d_ws, size_t ws_size,
                              hipStream_t stream) {
    const float* x     = (const float*)d_in[0];
    const float* gamma = (const float*)d_in[1];
    const float* beta  = (const float*)d_in[2];
    float* out = (float*)d_out;
    float* acc = (float*)d_ws;            // 1056 accum + 1056 result floats

    (void)hipMemsetAsync(acc, 0, 1056 * sizeof(float), stream);
    stats_kernel<<<GRID1, 256, 0, stream>>>(x, acc);
    newton_kernel<<<1, 1024, 0, stream>>>(acc, gamma, beta, acc + 1056);
    apply_kernel<<<(NTOT / 2) / 256, 256, 0, stream>>>(x, acc + 1056, out);
}

// Round 6
// 389.483 us; speedup vs baseline: 1.3031x; 1.3031x over previous
//
#include <hip/hip_runtime.h>
#include <stdint.h>

// Problem constants
constexpr int CIN  = 32;
constexpr int COLS_PER_B = 8192;               // COUT*ATOM
constexpr long long NTOT = 1048576;            // B * COLS_PER_B columns
constexpr float NTOTF = 1048576.0f;

typedef float f32x2 __attribute__((ext_vector_type(2)));

// Stats kernel tiling
constexpr int PAD   = 260;   // floats; 1040 B row stride: 16B-aligned, conflict-free (r3: ~0 conflicts)
constexpr int GRID1 = 512;   // 2 blocks/CU (66.5 KB LDS each)
constexpr int TPB   = 8;     // 4096 tiles / 512 blocks

// ws layout (floats): [0..1023] G accum, [1024..1055] s accum,
//                     [1056..2079] W (invsqrt*gamma), [2080..2111] bias

__global__ __launch_bounds__(256) void stats_kernel(const float* __restrict__ x,
                                                    float* __restrict__ acc) {
    __shared__ float tile[2][CIN * PAD];   // 66,560 B double buffer
    __shared__ float ssum[CIN];
    const int t = threadIdx.x;
    const int w = t >> 6;        // wave id = k-quarter
    const int l = t & 63;
    const int ti = l >> 3;       // 0..7
    const int tj = l & 7;        // 0..7

    float accg[4][4] = {};
    float asum[4] = {0.f, 0.f, 0.f, 0.f};
    if (t < CIN) ssum[t] = 0.f;

    const int tile0 = blockIdx.x * TPB;

    // Async global->LDS staging: no VGPR round-trip (round-4's stg[8] caused
    // VGPR=256 + 294MB scratch spill). Wave-uniform LDS base + lane*16B.
    auto stage = [&](int buf, int tileid) {
        const int b = tileid >> 5;               // 32 tiles per batch
        const int col0 = (tileid & 31) << 8;     // *256
        const float* base = x + (size_t)b * CIN * COLS_PER_B + col0 + l * 4;
        #pragma unroll
        for (int rr = 0; rr < 8; ++rr) {
            const int row = rr * 4 + w;          // wave w stages rows {w,4+w,...,28+w}
            const float* gp = base + (size_t)row * COLS_PER_B;
            __builtin_amdgcn_global_load_lds(
                (const __attribute__((address_space(1))) uint32_t*)gp,
                (__attribute__((address_space(3))) uint32_t*)&tile[buf][row * PAD],
                16, 0, 0);
        }
    };

    stage(0, tile0);
    __syncthreads();            // drain vmcnt: tile0 resident

    int buf = 0;
    for (int tt = 0; tt < TPB; ++tt) {
        if (tt + 1 < TPB) stage(buf ^ 1, tile0 + tt + 1);   // in flight during compute
        // compute current tile: wave w handles k in [w*64, w*64+64)
        #pragma unroll
        for (int s = 0; s < 16; ++s) {
            const int k = w * 64 + s * 4;
            float4 av[4], bv[4];
            #pragma unroll
            for (int d = 0; d < 4; ++d) av[d] = *(const float4*)(&tile[buf][(ti + 8 * d) * PAD + k]);
            #pragma unroll
            for (int d = 0; d < 4; ++d) bv[d] = *(const float4*)(&tile[buf][(tj + 8 * d) * PAD + k]);
            #pragma unroll
            for (int di = 0; di < 4; ++di) {
                asum[di] += av[di].x + av[di].y + av[di].z + av[di].w;
                #pragma unroll
                for (int dj = 0; dj < 4; ++dj) {
                    accg[di][dj] += av[di].x * bv[dj].x + av[di].y * bv[dj].y
                                  + av[di].z * bv[dj].z + av[di].w * bv[dj].w;
                }
            }
        }
        __syncthreads();   // drains vmcnt(0): next tile landed; readers done with buf
        buf ^= 1;
    }

    // cross-wave reduction of G partials via LDS (reuse tile as flat scratch)
    float* flat = &tile[0][0];
    #pragma unroll
    for (int di = 0; di < 4; ++di)
        #pragma unroll
        for (int dj = 0; dj < 4; ++dj)
            flat[w * 1024 + (ti + 8 * di) * 32 + (tj + 8 * dj)] = accg[di][dj];
    if (tj == 0) {
        #pragma unroll
        for (int di = 0; di < 4; ++di) atomicAdd(&ssum[ti + 8 * di], asum[di]);
    }
    __syncthreads();
    #pragma unroll
    for (int q = 0; q < 4; ++q) {
        const int idx = t + q * 256;
        const float v = flat[idx] + flat[1024 + idx] + flat[2048 + idx] + flat[3072 + idx];
        atomicAdd(&acc[idx], v);
    }
    if (t < CIN) atomicAdd(&acc[1024 + t], ssum[t]);
}

__global__ __launch_bounds__(1024) void newton_kernel(const float* __restrict__ acc,
                                                      const float* __restrict__ gamma,
                                                      const float* __restrict__ beta,
                                                      float* __restrict__ outp) {
    __shared__ float sn[32 * 33], p[32 * 33], t1[32 * 33], t2[32 * 33];
    __shared__ float mean[32], diag[32], trs[1];
    const int t = threadIdx.x;
    const int i = t >> 5, j = t & 31;

    if (t < 32) mean[t] = acc[1024 + t] * (1.0f / NTOTF);
    __syncthreads();
    const float sig = (acc[t] - NTOTF * mean[i] * mean[j]) * (1.0f / (NTOTF - 1.0f));
    if (i == j) diag[i] = sig;
    __syncthreads();
    if (t == 0) {
        float tr = 0.f;
        for (int k = 0; k < 32; ++k) tr += diag[k];
        trs[0] = tr;
    }
    __syncthreads();
    const float tr = trs[0];
    sn[i * 33 + j] = sig / tr;
    p[i * 33 + j]  = (i == j) ? 1.0f : 0.0f;
    __syncthreads();

    for (int it = 0; it < 5; ++it) {
        float a = 0.f;
        #pragma unroll
        for (int k = 0; k < 32; ++k) a += p[i * 33 + k] * p[k * 33 + j];
        t1[i * 33 + j] = a;
        __syncthreads();
        float c = 0.f;
        #pragma unroll
        for (int k = 0; k < 32; ++k) c += t1[i * 33 + k] * p[k * 33 + j];
        t2[i * 33 + j] = c;
        __syncthreads();
        float v = 0.f;
        #pragma unroll
        for (int k = 0; k < 32; ++k) v += t2[i * 33 + k] * sn[k * 33 + j];
        const float pn = 1.5f * p[i * 33 + j] - 0.5f * v;
        __syncthreads();
        p[i * 33 + j] = pn;
        __syncthreads();
    }

    const float r = rsqrtf(tr);
    const float wv = p[i * 33 + j] * r * gamma[j];   // fold gamma into W
    t1[i * 33 + j] = wv;
    outp[t] = wv;                                    // W: 1024 floats
    __syncthreads();
    if (t < 32) {
        float bb = beta[t];
        for (int k = 0; k < 32; ++k) bb -= mean[k] * t1[k * 33 + t];
        outp[1024 + t] = bb;                         // bias: 32 floats
    }
}

// Accumulate-per-i: acc[32] float2 (64 VGPR) + one in-flight x value.
// Compute starts after the FIRST load; compiler interleaves vmcnt(N) waits
// with 64-FMA blocks -> load latency hidden. ~85 VGPR, 4 waves/SIMD.
__global__ __launch_bounds__(256, 4) void apply_kernel(const float* __restrict__ x,
                                                       const float* __restrict__ wm,
                                                       float* __restrict__ out) {
    const size_t tid  = (size_t)blockIdx.x * 256 + threadIdx.x;
    const size_t col2 = tid * 2;          // 2 columns per thread
    const size_t b    = col2 >> 13;       // /8192
    const size_t c    = col2 & 8191;
    const float* xp = x + b * (size_t)(CIN * COLS_PER_B) + c;
    float* op       = out + b * (size_t)(CIN * COLS_PER_B) + c;

    float2 accv[32];
    #pragma unroll
    for (int j = 0; j < 32; ++j) {
        const float bv = wm[1024 + j];
        accv[j] = make_float2(bv, bv);
    }
    #pragma unroll
    for (int i = 0; i < 32; ++i) {
        const float2 v = *(const float2*)(xp + (size_t)i * COLS_PER_B);
        #pragma unroll
        for (int j = 0; j < 32; ++j) {
            const float sv = wm[i * 32 + j];  // wave-uniform -> SGPR broadcast
            accv[j].x += v.x * sv;
            accv[j].y += v.y * sv;
        }
    }
    // Nontemporal: out is write-once; don't evict L3-resident x.
    #pragma unroll
    for (int j = 0; j < 32; ++j) {
        f32x2 v = { accv[j].x, accv[j].y };
        __builtin_nontemporal_store(v, (f32x2*)(op + (size_t)j * COLS_PER_B));
    }
}

extern "C" void kernel_launch(void* const* d_in, const int* in_sizes, int n_in,
                              void* d_out, int out_size, void* d_ws, size_t ws_size,
                              hipStream_t stream) {
    const float* x     = (const float*)d_in[0];
    const float* gamma = (const float*)d_in[1];
    const float* beta  = (const float*)d_in[2];
    float* out = (float*)d_out;
    float* acc = (float*)d_ws;            // 1056 accum + 1056 result floats

    (void)hipMemsetAsync(acc, 0, 1056 * sizeof(float), stream);
    stats_kernel<<<GRID1, 256, 0, stream>>>(x, acc);
    newton_kernel<<<1, 1024, 0, stream>>>(acc, gamma, beta, acc + 1056);
    apply_kernel<<<(NTOT / 2) / 256, 256, 0, stream>>>(x, acc + 1056, out);
}